// Round 1
// baseline (69.041 us; speedup 1.0000x reference)
//
#include <hip/hip_runtime.h>
#include <math.h>

namespace fc {

constexpr float ACT_SCALE = 10.0f;
constexpr float U_HOVER   = 0.515025f;          // -MASS*-9.81/10/1/4
constexpr float INV_MASS  = 1.0f / 2.1f;
constexpr float GM        = 2.1f * -9.81f;      // MASS * GVEC_z
constexpr float KM        = 0.025f;
constexpr float TAUC      = 0.175f * 0.70710678f; // MOTOR_DIST / sqrt(2)
constexpr float JXY       = 0.0023f;
constexpr float JZ        = 0.004f;
constexpr float INV_JXY   = 1.0f / 0.0023f;     // == fp32 linalg.inv of diag
constexpr float INV_JZ    = 1.0f / 0.004f;
constexpr float G3        = -9.81f;
constexpr float INV_L     = 2.0f;               // /0.5 is exact *2
constexpr float DT        = 0.05f;
constexpr float DT2       = 0.05f * 0.5f;
constexpr float DT6       = 0.05f / 6.0f;

// r = v + 2*cross(qv, cross(qv,v) + s*v)
__device__ __forceinline__ void quatrot(float s, float ax, float ay, float az,
                                        float vx, float vy, float vz,
                                        float& rx, float& ry, float& rz) {
  float tx = ay * vz - az * vy + s * vx;
  float ty = az * vx - ax * vz + s * vy;
  float tz = ax * vy - ay * vx + s * vz;
  rx = vx + 2.0f * (ay * tz - az * ty);
  ry = vy + 2.0f * (az * tx - ax * tz);
  rz = vz + 2.0f * (ax * ty - ay * tx);
}

__device__ __forceinline__ void dyn(const float* xt,
                                    float Fz, float taux, float tauy, float tauz,
                                    float* dx) {
  float mx = xt[3], my = xt[4], mz = xt[5];
  float th = xt[6];
  float vx = xt[7], vy = xt[8], vz = xt[9];
  float wx = xt[10], wy = xt[11], wz = xt[12];

  float n2  = mx * mx + my * my + mz * mz;
  float inv = 1.0f / (1.0f + n2);
  float s   = (1.0f - n2) * inv;
  float qx  = 2.0f * mx * inv, qy = 2.0f * my * inv, qz = 2.0f * mz * inv;

  // f = (0,0,Fz) + quatrot(mrp2quat(-m), (0,0,MASS*g))
  float fx, fy, fzz;
  quatrot(s, -qx, -qy, -qz, 0.0f, 0.0f, GM, fx, fy, fzz);
  fzz += Fz;

  // pdot = quatrot(q, v)
  quatrot(s, qx, qy, qz, vx, vy, vz, dx[0], dx[1], dx[2]);

  // mdot = 0.25*((1-n2)*w + 2*cross(m,w) + 2*m*(m.w))
  float mw  = mx * wx + my * wy + mz * wz;
  float on2 = 1.0f - n2;
  dx[3] = 0.25f * (on2 * wx + 2.0f * (my * wz - mz * wy) + 2.0f * mx * mw);
  dx[4] = 0.25f * (on2 * wy + 2.0f * (mz * wx - mx * wz) + 2.0f * my * mw);
  dx[5] = 0.25f * (on2 * wz + 2.0f * (mx * wy - my * wx) + 2.0f * mz * mw);

  dx[6] = xt[13];  // theta_dot passthrough

  // vdot = f/MASS - cross(w,v)
  float vdx = fx * INV_MASS - (wy * vz - wz * vy);
  float vdy = fy * INV_MASS - (wz * vx - wx * vz);
  float vdz = fzz * INV_MASS - (wx * vy - wy * vx);
  dx[7] = vdx; dx[8] = vdy; dx[9] = vdz;

  // wdot = JINV*(tau - cross(w, J*w))
  float Jwx = JXY * wx, Jwy = JXY * wy, Jwz = JZ * wz;
  dx[10] = (taux - (wy * Jwz - wz * Jwy)) * INV_JXY;
  dx[11] = (tauy - (wz * Jwx - wx * Jwz)) * INV_JXY;
  dx[12] = (tauz - (wx * Jwy - wy * Jwx)) * INV_JZ;

  // theta_ddot = (g*sin(th) + quatrot(q,vdot).x * cos(th)) / L
  float rx, ry, rz;
  quatrot(s, qx, qy, qz, vdx, vdy, vdz, rx, ry, rz);
  float st = sinf(th), ct = cosf(th);
  dx[13] = (G3 * st + rx * ct) * INV_L;
}

__global__ __launch_bounds__(256) void fc_rk4_kernel(const float* __restrict__ x,
                                                     const float* __restrict__ u,
                                                     float* __restrict__ out,
                                                     int n) {
  __shared__ float xs[256 * 15];  // +1 pad -> stride 15, conflict-free reads
  const int t = threadIdx.x;
  const long long base = (long long)blockIdx.x * 256;
  long long rem = (long long)n - base;
  const int rows = rem > 256 ? 256 : (int)rem;
  const int nf = rows * 14;

  // --- stage x tile: coalesced float2 loads, scatter to padded LDS ---
  const float2* xg2 = (const float2*)(x + base * 14);
  #pragma unroll
  for (int k = 0; k < 7; ++k) {
    int f2 = t + k * 256;
    int f = f2 * 2;
    if (f < nf) {
      float2 v = xg2[f2];
      int r = f / 14;
      int c = f - r * 14;
      xs[r * 15 + c]     = v.x;
      xs[r * 15 + c + 1] = v.y;
    }
  }
  __syncthreads();

  float o[14];
  if (t < rows) {
    float x0[14];
    #pragma unroll
    for (int j = 0; j < 14; ++j) x0[j] = xs[t * 15 + j];

    // u row: direct coalesced float4
    float4 uv = ((const float4*)(u + base * 4))[t];
    float su0 = ACT_SCALE * (uv.x + U_HOVER);
    float su1 = ACT_SCALE * (uv.y + U_HOVER);
    float su2 = ACT_SCALE * (uv.z + U_HOVER);
    float su3 = ACT_SCALE * (uv.w + U_HOVER);

    // stage-invariant force/torque terms (hoisted out of dyn)
    float Fz   = ((su0 + su1) + su2) + su3;
    float tauz = KM * (((su0 - su1) + su2) - su3);
    float taux = ((TAUC * su0 + (-TAUC) * su1) + (-TAUC) * su2) + TAUC * su3;
    float tauy = (((-TAUC) * su0 + (-TAUC) * su1) + TAUC * su2) + TAUC * su3;

    float xt[14], kk[14], acc[14];
    dyn(x0, Fz, taux, tauy, tauz, kk);
    #pragma unroll
    for (int j = 0; j < 14; ++j) { acc[j] = kk[j]; xt[j] = x0[j] + DT2 * kk[j]; }
    dyn(xt, Fz, taux, tauy, tauz, kk);
    #pragma unroll
    for (int j = 0; j < 14; ++j) { acc[j] += 2.0f * kk[j]; xt[j] = x0[j] + DT2 * kk[j]; }
    dyn(xt, Fz, taux, tauy, tauz, kk);
    #pragma unroll
    for (int j = 0; j < 14; ++j) { acc[j] += 2.0f * kk[j]; xt[j] = x0[j] + DT * kk[j]; }
    dyn(xt, Fz, taux, tauy, tauz, kk);
    #pragma unroll
    for (int j = 0; j < 14; ++j) o[j] = x0[j] + DT6 * (acc[j] + kk[j]);
  }
  __syncthreads();  // done reading xs

  // --- stage output through LDS, coalesced float2 stores ---
  if (t < rows) {
    #pragma unroll
    for (int j = 0; j < 14; ++j) xs[t * 15 + j] = o[j];
  }
  __syncthreads();

  float2* og2 = (float2*)(out + base * 14);
  #pragma unroll
  for (int k = 0; k < 7; ++k) {
    int f2 = t + k * 256;
    int f = f2 * 2;
    if (f < nf) {
      int r = f / 14;
      int c = f - r * 14;
      og2[f2] = make_float2(xs[r * 15 + c], xs[r * 15 + c + 1]);
    }
  }
}

}  // namespace fc

extern "C" void kernel_launch(void* const* d_in, const int* in_sizes, int n_in,
                              void* d_out, int out_size, void* d_ws, size_t ws_size,
                              hipStream_t stream) {
  const float* x = (const float*)d_in[0];
  const float* u = (const float*)d_in[1];
  float* out = (float*)d_out;
  const int n = in_sizes[0] / 14;  // batch rows
  const int grid = (n + 255) / 256;
  hipLaunchKernelGGL(fc::fc_rk4_kernel, dim3(grid), dim3(256), 0, stream,
                     x, u, out, n);
}

// Round 3
// 60.998 us; speedup vs baseline: 1.1319x; 1.1319x over previous
//
#include <hip/hip_runtime.h>
#include <math.h>

namespace fc {

typedef float vf4 __attribute__((ext_vector_type(4)));  // native vec: OK for nontemporal builtins

constexpr float ACT_SCALE = 10.0f;
constexpr float U_HOVER   = 0.515025f;          // -MASS*-9.81/10/1/4
constexpr float INV_MASS  = 1.0f / 2.1f;
constexpr float GM        = 2.1f * -9.81f;      // MASS * GVEC_z
constexpr float KM        = 0.025f;
constexpr float TAUC      = 0.175f * 0.70710678f; // MOTOR_DIST / sqrt(2)
constexpr float JXY       = 0.0023f;
constexpr float JZ        = 0.004f;
constexpr float INV_JXY   = 1.0f / 0.0023f;
constexpr float INV_JZ    = 1.0f / 0.004f;
constexpr float G3        = -9.81f;
constexpr float INV_L     = 2.0f;
constexpr float DT        = 0.05f;
constexpr float DT2       = 0.05f * 0.5f;
constexpr float DT6       = 0.05f / 6.0f;

__device__ __forceinline__ void quatrot(float s, float ax, float ay, float az,
                                        float vx, float vy, float vz,
                                        float& rx, float& ry, float& rz) {
  float tx = ay * vz - az * vy + s * vx;
  float ty = az * vx - ax * vz + s * vy;
  float tz = ax * vy - ay * vx + s * vz;
  rx = vx + 2.0f * (ay * tz - az * ty);
  ry = vy + 2.0f * (az * tx - ax * tz);
  rz = vz + 2.0f * (ax * ty - ay * tx);
}

__device__ __forceinline__ void dyn(const float* xt,
                                    float Fz, float taux, float tauy, float tauz,
                                    float* dx) {
  float mx = xt[3], my = xt[4], mz = xt[5];
  float th = xt[6];
  float vx = xt[7], vy = xt[8], vz = xt[9];
  float wx = xt[10], wy = xt[11], wz = xt[12];

  float n2  = mx * mx + my * my + mz * mz;
  float inv = 1.0f / (1.0f + n2);
  float s   = (1.0f - n2) * inv;
  float qx  = 2.0f * mx * inv, qy = 2.0f * my * inv, qz = 2.0f * mz * inv;

  float fx, fy, fzz;
  quatrot(s, -qx, -qy, -qz, 0.0f, 0.0f, GM, fx, fy, fzz);
  fzz += Fz;

  quatrot(s, qx, qy, qz, vx, vy, vz, dx[0], dx[1], dx[2]);

  float mw  = mx * wx + my * wy + mz * wz;
  float on2 = 1.0f - n2;
  dx[3] = 0.25f * (on2 * wx + 2.0f * (my * wz - mz * wy) + 2.0f * mx * mw);
  dx[4] = 0.25f * (on2 * wy + 2.0f * (mz * wx - mx * wz) + 2.0f * my * mw);
  dx[5] = 0.25f * (on2 * wz + 2.0f * (mx * wy - my * wx) + 2.0f * mz * mw);

  dx[6] = xt[13];

  float vdx = fx * INV_MASS - (wy * vz - wz * vy);
  float vdy = fy * INV_MASS - (wz * vx - wx * vz);
  float vdz = fzz * INV_MASS - (wx * vy - wy * vx);
  dx[7] = vdx; dx[8] = vdy; dx[9] = vdz;

  float Jwx = JXY * wx, Jwy = JXY * wy, Jwz = JZ * wz;
  dx[10] = (taux - (wy * Jwz - wz * Jwy)) * INV_JXY;
  dx[11] = (tauy - (wz * Jwx - wx * Jwz)) * INV_JXY;
  dx[12] = (tauz - (wx * Jwy - wy * Jwx)) * INV_JZ;

  float rx, ry, rz;
  quatrot(s, qx, qy, qz, vdx, vdy, vdz, rx, ry, rz);
  float st = sinf(th), ct = cosf(th);
  dx[13] = (G3 * st + rx * ct) * INV_L;
}

__device__ __forceinline__ void rk4_row(const float* x0, float4 uv, float* o) {
  float su0 = ACT_SCALE * (uv.x + U_HOVER);
  float su1 = ACT_SCALE * (uv.y + U_HOVER);
  float su2 = ACT_SCALE * (uv.z + U_HOVER);
  float su3 = ACT_SCALE * (uv.w + U_HOVER);

  float Fz   = ((su0 + su1) + su2) + su3;
  float tauz = KM * (((su0 - su1) + su2) - su3);
  float taux = ((TAUC * su0 + (-TAUC) * su1) + (-TAUC) * su2) + TAUC * su3;
  float tauy = (((-TAUC) * su0 + (-TAUC) * su1) + TAUC * su2) + TAUC * su3;

  float xt[14], kk[14], acc[14];
  dyn(x0, Fz, taux, tauy, tauz, kk);
  #pragma unroll
  for (int j = 0; j < 14; ++j) { acc[j] = kk[j]; xt[j] = x0[j] + DT2 * kk[j]; }
  dyn(xt, Fz, taux, tauy, tauz, kk);
  #pragma unroll
  for (int j = 0; j < 14; ++j) { acc[j] += 2.0f * kk[j]; xt[j] = x0[j] + DT2 * kk[j]; }
  dyn(xt, Fz, taux, tauy, tauz, kk);
  #pragma unroll
  for (int j = 0; j < 14; ++j) { acc[j] += 2.0f * kk[j]; xt[j] = x0[j] + DT * kk[j]; }
  dyn(xt, Fz, taux, tauy, tauz, kk);
  #pragma unroll
  for (int j = 0; j < 14; ++j) o[j] = x0[j] + DT6 * (acc[j] + kk[j]);
}

__global__ __launch_bounds__(256) void fc_rk4_kernel(const float* __restrict__ x,
                                                     const float* __restrict__ u,
                                                     float* __restrict__ out,
                                                     int n) {
  __shared__ float xs[256 * 14];  // linear tile: exact copy of global layout
  const int t = threadIdx.x;
  const long long base = (long long)blockIdx.x * 256;

  if (base + 256 <= (long long)n) {
    // ---- full block: vf4 linear staging (coalesced, conflict-free) ----
    const vf4* xg4 = (const vf4*)(x + base * 14);
    vf4* xs4 = (vf4*)xs;
    // 256*14 floats = 896 vf4
    xs4[t]       = __builtin_nontemporal_load(xg4 + t);
    xs4[t + 256] = __builtin_nontemporal_load(xg4 + t + 256);
    xs4[t + 512] = __builtin_nontemporal_load(xg4 + t + 512);
    if (t < 128) xs4[t + 768] = __builtin_nontemporal_load(xg4 + t + 768);
    __syncthreads();

    // per-thread row: 7x ds_read_b64 (stride-14 rows, ~4-way, cheap)
    float x0[14];
    const float2* r2 = (const float2*)(xs + t * 14);
    #pragma unroll
    for (int j = 0; j < 7; ++j) {
      float2 v = r2[j];
      x0[2 * j] = v.x; x0[2 * j + 1] = v.y;
    }

    float4 uv = ((const float4*)(u + base * 4))[t];
    float o[14];
    rk4_row(x0, uv, o);

    // write back into own row region (no cross-thread hazard -> no barrier)
    float2* w2 = (float2*)(xs + t * 14);
    #pragma unroll
    for (int j = 0; j < 7; ++j) w2[j] = make_float2(o[2 * j], o[2 * j + 1]);
    __syncthreads();

    // vf4 linear drain, nontemporal (don't evict input stream from L3)
    vf4* og4 = (vf4*)(out + base * 14);
    __builtin_nontemporal_store(xs4[t], og4 + t);
    __builtin_nontemporal_store(xs4[t + 256], og4 + t + 256);
    __builtin_nontemporal_store(xs4[t + 512], og4 + t + 512);
    if (t < 128) __builtin_nontemporal_store(xs4[t + 768], og4 + t + 768);
  } else {
    // ---- tail block (not hit for B=2M, kept for correctness) ----
    long long row = base + t;
    if (row < n) {
      float x0[14];
      const float2* g2 = (const float2*)(x + row * 14);
      #pragma unroll
      for (int j = 0; j < 7; ++j) {
        float2 v = g2[j];
        x0[2 * j] = v.x; x0[2 * j + 1] = v.y;
      }
      float4 uv = ((const float4*)(u + row * 4))[0];
      float o[14];
      rk4_row(x0, uv, o);
      float2* o2 = (float2*)(out + row * 14);
      #pragma unroll
      for (int j = 0; j < 7; ++j) o2[j] = make_float2(o[2 * j], o[2 * j + 1]);
    }
  }
}

}  // namespace fc

extern "C" void kernel_launch(void* const* d_in, const int* in_sizes, int n_in,
                              void* d_out, int out_size, void* d_ws, size_t ws_size,
                              hipStream_t stream) {
  const float* x = (const float*)d_in[0];
  const float* u = (const float*)d_in[1];
  float* out = (float*)d_out;
  const int n = in_sizes[0] / 14;
  const int grid = (n + 255) / 256;
  hipLaunchKernelGGL(fc::fc_rk4_kernel, dim3(grid), dim3(256), 0, stream,
                     x, u, out, n);
}

// Round 4
// 55.421 us; speedup vs baseline: 1.2457x; 1.1006x over previous
//
#include <hip/hip_runtime.h>
#include <math.h>

namespace fc {

typedef float vf4 __attribute__((ext_vector_type(4)));  // native vec: OK for nontemporal builtins

constexpr float ACT_SCALE = 10.0f;
constexpr float U_HOVER   = 0.515025f;          // -MASS*-9.81/10/1/4
constexpr float INV_MASS  = 1.0f / 2.1f;
constexpr float GM        = 2.1f * -9.81f;      // MASS * GVEC_z
constexpr float KM        = 0.025f;
constexpr float TAUC      = 0.175f * 0.70710678f; // MOTOR_DIST / sqrt(2)
constexpr float JXY       = 0.0023f;
constexpr float JZ        = 0.004f;
constexpr float INV_JXY   = 1.0f / 0.0023f;
constexpr float INV_JZ    = 1.0f / 0.004f;
constexpr float G3        = -9.81f;
constexpr float INV_L     = 2.0f;
constexpr float DT        = 0.05f;
constexpr float DT2       = 0.05f * 0.5f;
constexpr float DT6       = 0.05f / 6.0f;

__device__ __forceinline__ void quatrot(float s, float ax, float ay, float az,
                                        float vx, float vy, float vz,
                                        float& rx, float& ry, float& rz) {
  float tx = ay * vz - az * vy + s * vx;
  float ty = az * vx - ax * vz + s * vy;
  float tz = ax * vy - ay * vx + s * vz;
  rx = vx + 2.0f * (ay * tz - az * ty);
  ry = vy + 2.0f * (az * tx - ax * tz);
  rz = vz + 2.0f * (ax * ty - ay * tx);
}

__device__ __forceinline__ void dyn(const float* xt,
                                    float Fz, float taux, float tauy, float tauz,
                                    float* dx) {
  float mx = xt[3], my = xt[4], mz = xt[5];
  float th = xt[6];
  float vx = xt[7], vy = xt[8], vz = xt[9];
  float wx = xt[10], wy = xt[11], wz = xt[12];

  float n2  = mx * mx + my * my + mz * mz;
  float inv = __builtin_amdgcn_rcpf(1.0f + n2);   // ~1e-7 rel err, 1 inst
  float s   = (1.0f - n2) * inv;
  float qx  = 2.0f * mx * inv, qy = 2.0f * my * inv, qz = 2.0f * mz * inv;

  float fx, fy, fzz;
  quatrot(s, -qx, -qy, -qz, 0.0f, 0.0f, GM, fx, fy, fzz);
  fzz += Fz;

  quatrot(s, qx, qy, qz, vx, vy, vz, dx[0], dx[1], dx[2]);

  float mw  = mx * wx + my * wy + mz * wz;
  float on2 = 1.0f - n2;
  dx[3] = 0.25f * (on2 * wx + 2.0f * (my * wz - mz * wy) + 2.0f * mx * mw);
  dx[4] = 0.25f * (on2 * wy + 2.0f * (mz * wx - mx * wz) + 2.0f * my * mw);
  dx[5] = 0.25f * (on2 * wz + 2.0f * (mx * wy - my * wx) + 2.0f * mz * mw);

  dx[6] = xt[13];

  float vdx = fx * INV_MASS - (wy * vz - wz * vy);
  float vdy = fy * INV_MASS - (wz * vx - wx * vz);
  float vdz = fzz * INV_MASS - (wx * vy - wy * vx);
  dx[7] = vdx; dx[8] = vdy; dx[9] = vdz;

  float Jwx = JXY * wx, Jwy = JXY * wy, Jwz = JZ * wz;
  dx[10] = (taux - (wy * Jwz - wz * Jwy)) * INV_JXY;
  dx[11] = (tauy - (wz * Jwx - wx * Jwz)) * INV_JXY;
  dx[12] = (tauz - (wx * Jwy - wy * Jwx)) * INV_JZ;

  float rx, ry, rz;
  quatrot(s, qx, qy, qz, vdx, vdy, vdz, rx, ry, rz);
  float st = __sinf(th), ct = __cosf(th);    // v_sin_f32/v_cos_f32 (~2 inst each)
  dx[13] = (G3 * st + rx * ct) * INV_L;
}

__device__ __forceinline__ void rk4_row(const float* x0, float4 uv, float* o) {
  float su0 = ACT_SCALE * (uv.x + U_HOVER);
  float su1 = ACT_SCALE * (uv.y + U_HOVER);
  float su2 = ACT_SCALE * (uv.z + U_HOVER);
  float su3 = ACT_SCALE * (uv.w + U_HOVER);

  float Fz   = ((su0 + su1) + su2) + su3;
  float tauz = KM * (((su0 - su1) + su2) - su3);
  float taux = ((TAUC * su0 + (-TAUC) * su1) + (-TAUC) * su2) + TAUC * su3;
  float tauy = (((-TAUC) * su0 + (-TAUC) * su1) + TAUC * su2) + TAUC * su3;

  float xt[14], kk[14], acc[14];
  dyn(x0, Fz, taux, tauy, tauz, kk);
  #pragma unroll
  for (int j = 0; j < 14; ++j) { acc[j] = kk[j]; xt[j] = x0[j] + DT2 * kk[j]; }
  dyn(xt, Fz, taux, tauy, tauz, kk);
  #pragma unroll
  for (int j = 0; j < 14; ++j) { acc[j] += 2.0f * kk[j]; xt[j] = x0[j] + DT2 * kk[j]; }
  dyn(xt, Fz, taux, tauy, tauz, kk);
  #pragma unroll
  for (int j = 0; j < 14; ++j) { acc[j] += 2.0f * kk[j]; xt[j] = x0[j] + DT * kk[j]; }
  dyn(xt, Fz, taux, tauy, tauz, kk);
  #pragma unroll
  for (int j = 0; j < 14; ++j) o[j] = x0[j] + DT6 * (acc[j] + kk[j]);
}

__global__ __launch_bounds__(256) void fc_rk4_kernel(const float* __restrict__ x,
                                                     const float* __restrict__ u,
                                                     float* __restrict__ out,
                                                     int n) {
  __shared__ float xs[256 * 14];  // linear tile: exact copy of global layout
  const int t = threadIdx.x;
  const long long base = (long long)blockIdx.x * 256;

  if (base + 256 <= (long long)n) {
    // ---- full block: vf4 linear staging (coalesced, conflict-free) ----
    const vf4* xg4 = (const vf4*)(x + base * 14);
    vf4* xs4 = (vf4*)xs;
    // 256*14 floats = 896 vf4
    xs4[t]       = __builtin_nontemporal_load(xg4 + t);
    xs4[t + 256] = __builtin_nontemporal_load(xg4 + t + 256);
    xs4[t + 512] = __builtin_nontemporal_load(xg4 + t + 512);
    if (t < 128) xs4[t + 768] = __builtin_nontemporal_load(xg4 + t + 768);
    __syncthreads();

    // per-thread row: 7x ds_read_b64 (stride-14 rows, ~4-way, cheap)
    float x0[14];
    const float2* r2 = (const float2*)(xs + t * 14);
    #pragma unroll
    for (int j = 0; j < 7; ++j) {
      float2 v = r2[j];
      x0[2 * j] = v.x; x0[2 * j + 1] = v.y;
    }

    float4 uv = ((const float4*)(u + base * 4))[t];
    float o[14];
    rk4_row(x0, uv, o);

    // write back into own row region (no cross-thread hazard -> no barrier)
    float2* w2 = (float2*)(xs + t * 14);
    #pragma unroll
    for (int j = 0; j < 7; ++j) w2[j] = make_float2(o[2 * j], o[2 * j + 1]);
    __syncthreads();

    // vf4 linear drain, nontemporal (don't evict input stream from L3)
    vf4* og4 = (vf4*)(out + base * 14);
    __builtin_nontemporal_store(xs4[t], og4 + t);
    __builtin_nontemporal_store(xs4[t + 256], og4 + t + 256);
    __builtin_nontemporal_store(xs4[t + 512], og4 + t + 512);
    if (t < 128) __builtin_nontemporal_store(xs4[t + 768], og4 + t + 768);
  } else {
    // ---- tail block (not hit for B=2M, kept for correctness) ----
    long long row = base + t;
    if (row < n) {
      float x0[14];
      const float2* g2 = (const float2*)(x + row * 14);
      #pragma unroll
      for (int j = 0; j < 7; ++j) {
        float2 v = g2[j];
        x0[2 * j] = v.x; x0[2 * j + 1] = v.y;
      }
      float4 uv = ((const float4*)(u + row * 4))[0];
      float o[14];
      rk4_row(x0, uv, o);
      float2* o2 = (float2*)(out + row * 14);
      #pragma unroll
      for (int j = 0; j < 7; ++j) o2[j] = make_float2(o[2 * j], o[2 * j + 1]);
    }
  }
}

}  // namespace fc

extern "C" void kernel_launch(void* const* d_in, const int* in_sizes, int n_in,
                              void* d_out, int out_size, void* d_ws, size_t ws_size,
                              hipStream_t stream) {
  const float* x = (const float*)d_in[0];
  const float* u = (const float*)d_in[1];
  float* out = (float*)d_out;
  const int n = in_sizes[0] / 14;
  const int grid = (n + 255) / 256;
  hipLaunchKernelGGL(fc::fc_rk4_kernel, dim3(grid), dim3(256), 0, stream,
                     x, u, out, n);
}